// Round 13
// baseline (781.664 us; speedup 1.0000x reference)
//
#include <hip/hip_runtime.h>

// ---------------------------------------------------------------------------
// Transformer block, f32-faithful pre-gate pipeline. Split-fp16 GEMMs are
// reformulated as VIRTUAL-K single-f16 GEMMs (K'=3K phases: Ah*Bh, Al*Bh,
// Ah*Bl) so they share one 256x256-tile kernel: 8 waves (2x4, 128x64 each),
// BK=64, double-buffered 128KB LDS, stage(t+1) issued under MFMA, one
// syncthreads per iter. N=1024 K-heavy GEMMs are K-split x4 into f32
// partials + reduce4. MoE: f32 gate/argmax, dense 256-row tile plan.
// Attention: V pre-transposed in QKV epilogue; Q frags in regs.
// ---------------------------------------------------------------------------

using f16   = _Float16;
using f16x4 = __attribute__((ext_vector_type(4))) _Float16;
using f16x8 = __attribute__((ext_vector_type(8))) _Float16;
using f32x4 = __attribute__((ext_vector_type(4))) float;

__device__ __forceinline__ void async16(void* l, const void* g) {
  __builtin_amdgcn_global_load_lds(
      (const __attribute__((address_space(1))) unsigned*)g,
      (__attribute__((address_space(3))) unsigned*)l, 16, 0, 0);
}

// ---------------- weight transpose f32[R][Cc] -> f16 (hi[,lo]) [Cc][R] ------
template <bool SPLITW>
__global__ __launch_bounds__(256) void transpose_k(
    const float* __restrict__ in, f16* __restrict__ oh, f16* __restrict__ ol,
    int R, int Cc) {
  const size_t bofs = (size_t)blockIdx.y * R * Cc;
  in += bofs; oh += bofs;
  if constexpr (SPLITW) ol += bofs;
  __shared__ float tile[32][33];
  const int nbx = Cc >> 5;
  const int bx = blockIdx.x % nbx, by = blockIdx.x / nbx;
  const int tx = threadIdx.x & 31, ty = threadIdx.x >> 5;
#pragma unroll
  for (int i = 0; i < 4; ++i) {
    int r = ty + i * 8;
    tile[r][tx] = in[(size_t)(by * 32 + r) * Cc + bx * 32 + tx];
  }
  __syncthreads();
#pragma unroll
  for (int i = 0; i < 4; ++i) {
    int oc = ty + i * 8;
    float v = tile[tx][oc];
    size_t o = (size_t)(bx * 32 + oc) * R + by * 32 + tx;
    f16 hi = (f16)v;
    oh[o] = hi;
    if constexpr (SPLITW) ol[o] = (f16)(v - (float)hi);
  }
}

// ---------------- LayerNorm f32 -> split f16 pair, row length 1024 ----------
__global__ __launch_bounds__(256) void ln_k(
    const float* __restrict__ x, const float* __restrict__ g,
    const float* __restrict__ b, f16* __restrict__ outh, f16* __restrict__ outl) {
  const int row = blockIdx.x;
  const float4 vv = ((const float4*)(x + (size_t)row * 1024))[threadIdx.x];
  float s = vv.x + vv.y + vv.z + vv.w;
  float sq = vv.x * vv.x + vv.y * vv.y + vv.z * vv.z + vv.w * vv.w;
#pragma unroll
  for (int mm = 32; mm; mm >>= 1) { s += __shfl_xor(s, mm); sq += __shfl_xor(sq, mm); }
  __shared__ float red[8];
  const int wv = threadIdx.x >> 6;
  if ((threadIdx.x & 63) == 0) { red[wv] = s; red[4 + wv] = sq; }
  __syncthreads();
  s = red[0] + red[1] + red[2] + red[3];
  sq = red[4] + red[5] + red[6] + red[7];
  const float mean = s * 0.0009765625f;
  const float rstd = rsqrtf(sq * 0.0009765625f - mean * mean + 1e-5f);
  const int c = threadIdx.x * 4;
  const float xs[4] = {vv.x, vv.y, vv.z, vv.w};
  f16x4 ovh, ovl;
#pragma unroll
  for (int i = 0; i < 4; ++i) {
    float val = (xs[i] - mean) * rstd * g[c + i] + b[c + i];
    f16 hi = (f16)val;
    ovh[i] = hi;
    ovl[i] = (f16)(val - (float)hi);
  }
  *(f16x4*)(outh + (size_t)row * 1024 + c) = ovh;
  *(f16x4*)(outl + (size_t)row * 1024 + c) = ovl;
}

// ---------------- gate: f32 LN + h@gate_w + argmax + routing ----------------
__global__ __launch_bounds__(256) void gate_k(
    const float* __restrict__ x, const float* __restrict__ g, const float* __restrict__ b,
    const float* __restrict__ gw, const float* __restrict__ gb,
    int* __restrict__ cnt, int* __restrict__ idxAll, int* __restrict__ eid) {
  const int t = blockIdx.x;
  const float4 vv = ((const float4*)(x + (size_t)t * 1024))[threadIdx.x];
  float s = vv.x + vv.y + vv.z + vv.w;
  float sq = vv.x * vv.x + vv.y * vv.y + vv.z * vv.z + vv.w * vv.w;
#pragma unroll
  for (int mm = 32; mm; mm >>= 1) { s += __shfl_xor(s, mm); sq += __shfl_xor(sq, mm); }
  __shared__ float red[8];
  __shared__ float redv[4][4];
  const int wv = threadIdx.x >> 6;
  if ((threadIdx.x & 63) == 0) { red[wv] = s; red[4 + wv] = sq; }
  __syncthreads();
  s = red[0] + red[1] + red[2] + red[3];
  sq = red[4] + red[5] + red[6] + red[7];
  const float mean = s * 0.0009765625f;
  const float rstd = rsqrtf(sq * 0.0009765625f - mean * mean + 1e-5f);
  const int c = threadIdx.x * 4;
  const float xs[4] = {vv.x, vv.y, vv.z, vv.w};
  float a0 = 0.f, a1 = 0.f, a2 = 0.f, a3 = 0.f;
#pragma unroll
  for (int i = 0; i < 4; ++i) {
    float ln = (xs[i] - mean) * rstd * g[c + i] + b[c + i];
    const float4 w4 = ((const float4*)gw)[c + i];
    a0 += ln * w4.x; a1 += ln * w4.y; a2 += ln * w4.z; a3 += ln * w4.w;
  }
#pragma unroll
  for (int mm = 32; mm; mm >>= 1) {
    a0 += __shfl_xor(a0, mm); a1 += __shfl_xor(a1, mm);
    a2 += __shfl_xor(a2, mm); a3 += __shfl_xor(a3, mm);
  }
  if ((threadIdx.x & 63) == 0) {
    redv[wv][0] = a0; redv[wv][1] = a1; redv[wv][2] = a2; redv[wv][3] = a3;
  }
  __syncthreads();
  if (threadIdx.x == 0) {
    float ge[4];
#pragma unroll
    for (int e = 0; e < 4; ++e)
      ge[e] = redv[0][e] + redv[1][e] + redv[2][e] + redv[3][e] + gb[e];
    int be = 0; float bvv = ge[0];
#pragma unroll
    for (int e = 1; e < 4; ++e) if (ge[e] > bvv) { bvv = ge[e]; be = e; }
    int pos = atomicAdd(&cnt[be], 1);
    idxAll[(be << 12) + pos] = t;
    eid[t] = be;
  }
}

__global__ void init_moe(int* cnt) { if (threadIdx.x < 4) cnt[threadIdx.x] = 0; }

// ---------------- plan: cnt[] -> dense 256-row m-tile descriptors -----------
#define MAXMT 20
__global__ void plan_k(const int* __restrict__ cnt, int* __restrict__ desc) {
  if (threadIdx.x == 0) {
    int t = 0;
    for (int e = 0; e < 4; ++e) {
      const int c = cnt[e];
      for (int m = 0; m < c; m += 256) desc[t++] = (e << 16) | (m >> 8);
    }
    for (; t < MAXMT; ++t) desc[t] = -1;
  }
}

// ---------------- reduce4: out = res + p0+p1+p2+p3 + bias -------------------
template <bool MOE>
__global__ __launch_bounds__(256) void reduce_k(
    const float* __restrict__ p0, const float* __restrict__ p1,
    const float* __restrict__ p2, const float* __restrict__ p3,
    const float* __restrict__ res, const float* __restrict__ bias,
    const int* __restrict__ eid, float* __restrict__ o) {
  const int row = blockIdx.x, t = threadIdx.x;
  const float* bp = MOE ? bias + (size_t)eid[row] * 1024 : bias;
  const float4 a = ((const float4*)(p0 + (size_t)row * 1024))[t];
  const float4 b = ((const float4*)(p1 + (size_t)row * 1024))[t];
  const float4 c = ((const float4*)(p2 + (size_t)row * 1024))[t];
  const float4 d = ((const float4*)(p3 + (size_t)row * 1024))[t];
  const float4 r = ((const float4*)(res + (size_t)row * 1024))[t];
  const float4 bb = ((const float4*)bp)[t];
  float4 o4;
  o4.x = r.x + a.x + b.x + c.x + d.x + bb.x;
  o4.y = r.y + a.y + b.y + c.y + d.y + bb.y;
  o4.z = r.z + a.z + b.z + c.z + d.z + bb.z;
  o4.w = r.w + a.w + b.w + c.w + d.w + bb.w;
  ((float4*)(o + (size_t)row * 1024))[t] = o4;
}

// ---------------- 256x256 f16 MFMA GEMM, 8 waves, dbuf, virtual-K split -----
// A[M][K], Bt[N][K]. SPLIT: virtual K'=3K phases (Ah*Bh, Al*Bh, Ah*Bl).
// OUT: 0=f32 (p0), 1=split f16 pair, 2=single f16, 3=f32 partial (p[ks]).
// QKV3: q/k written [buf][tok][1024]; v third transposed v_t[(b*16+h)][d][t].
// GATHER: dense 256-row m-tile plan in desc[]. KS: K split into KS parts.
template <bool SPLIT, bool RELU, bool BIAS, bool RES, bool GATHER, int OUT,
          bool QKV3, int KS>
__global__ __launch_bounds__(512, 1) void gemm_k(
    const f16* __restrict__ Ah, const f16* __restrict__ Al,
    const f16* __restrict__ Bh, const f16* __restrict__ Bl,
    float* __restrict__ p0, float* __restrict__ p1,
    float* __restrict__ p2, float* __restrict__ p3,
    f16* __restrict__ outh, f16* __restrict__ outl,
    const float* __restrict__ bias, const float* __restrict__ res,
    const int* __restrict__ idxAll, const int* __restrict__ cntAll,
    const int* __restrict__ desc,
    int M, int N, int K) {
  const int NB = N >> 8;
  int m0, n0, ks = 0;
  int cnt = M;
  const int* idx = nullptr;
  if constexpr (GATHER) {
    int rem = blockIdx.x;
    if constexpr (KS > 1) {
      const int per = (int)gridDim.x / KS;
      ks = rem / per; rem -= ks * per;
    }
    const int mt = rem / NB, nt = rem - mt * NB;
    const int d = desc[mt];
    if (d < 0) return;
    const int e = d >> 16;
    m0 = (d & 0xffff) << 8;
    n0 = nt << 8;
    cnt = cntAll[e];
    idx = idxAll + (e << 12);
    Bh += (size_t)e * N * K;
    if constexpr (SPLIT) Bl += (size_t)e * N * K;
    if (BIAS) bias += (size_t)e * N;
  } else {
    int rem = blockIdx.x;
    const int ntile = (int)gridDim.x / KS;
    if constexpr (KS > 1) { ks = rem / ntile; rem -= ks * ntile; }
    const int q = ntile >> 3;                    // ntile % 8 == 0 for our grids
    const int bid = (rem & 7) * q + (rem >> 3);  // XCD-bijective
    m0 = (bid / NB) << 8; n0 = (bid % NB) << 8;
  }

  // [2 buf][A 32KB | B 32KB]
  __shared__ __align__(16) char lds[131072];

  const int tid = threadIdx.x;
  const int wave = tid >> 6, lane = tid & 63;
  const int wm = wave >> 2, wn = wave & 3;   // 2 x 4 wave grid, 128x64 each
  const int srow = lane >> 3, l7 = lane & 7;
  const int kofs = (l7 ^ srow) << 4;         // pre-swizzled source chunk

  const int Kp = K / KS;
  const int kshift = ks * Kp;
  const int ntk = Kp >> 6;
  const int nt = SPLIT ? 3 * ntk : ntk;

  // per-thread staging byte offsets (relative to operand base)
  unsigned offA[4], offB[4];
#pragma unroll
  for (int s = 0; s < 4; ++s) {
    const int ar = wave * 32 + s * 8 + srow;   // 0..255
    int gm = m0 + ar;
    if constexpr (GATHER) gm = idx[gm < cnt ? gm : cnt - 1];
    offA[s] = (unsigned)(((size_t)gm * K + kshift) * 2) + kofs;
    offB[s] = (unsigned)(((size_t)(n0 + ar) * K + kshift) * 2) + kofs;
  }

  const char* const baseAh = (const char*)Ah;
  const char* const baseAl = (const char*)Al;
  const char* const baseBh = (const char*)Bh;
  const char* const baseBl = (const char*)Bl;

  auto stage = [&](int tile, int buf) {
    int p = 0, kt = tile;
    if constexpr (SPLIT) {
      p = (tile >= 2 * ntk) ? 2 : (tile >= ntk ? 1 : 0);
      kt = tile - p * ntk;
    }
    const char* bA = (SPLIT && p == 1) ? baseAl : baseAh;
    const char* bB = (SPLIT && p == 2) ? baseBl : baseBh;
    const unsigned kb = (unsigned)kt << 7;     // kt*64 elems *2B
    char* dst = lds + buf * 65536 + wave * 4096;
#pragma unroll
    for (int s = 0; s < 4; ++s) {
      async16(dst + s * 1024, bA + offA[s] + kb);
      async16(dst + 32768 + s * 1024, bB + offB[s] + kb);
    }
  };

  // fragment read offsets
  const int s4 = lane >> 4, fr = lane & 15;
  int roA[8], roB[4];
#pragma unroll
  for (int i = 0; i < 8; ++i) roA[i] = (wm * 128 + i * 16 + fr) * 128;
#pragma unroll
  for (int j = 0; j < 4; ++j) roB[j] = 32768 + (wn * 64 + j * 16 + fr) * 128;
  const int ch0 = (s4 ^ l7) << 4;
  const int ch1 = ((4 + s4) ^ l7) << 4;

  f32x4 acc[8][4] = {};

  stage(0, 0);
  __syncthreads();

  for (int t = 0; t < nt; ++t) {
    const char* cb = lds + (t & 1) * 65536;
    // kk = 0 fragment reads
    f16x8 a[8], b[4];
#pragma unroll
    for (int i = 0; i < 8; ++i) a[i] = *(const f16x8*)(cb + roA[i] + ch0);
#pragma unroll
    for (int j = 0; j < 4; ++j) b[j] = *(const f16x8*)(cb + roB[j] + ch0);
    // issue next-tile stage under this iter's MFMAs
    if (t + 1 < nt) stage(t + 1, (t + 1) & 1);
    __builtin_amdgcn_s_setprio(1);
#pragma unroll
    for (int i = 0; i < 8; ++i)
#pragma unroll
      for (int j = 0; j < 4; ++j)
        acc[i][j] = __builtin_amdgcn_mfma_f32_16x16x32_f16(a[i], b[j], acc[i][j], 0, 0, 0);
    __builtin_amdgcn_s_setprio(0);
    // kk = 1
#pragma unroll
    for (int i = 0; i < 8; ++i) a[i] = *(const f16x8*)(cb + roA[i] + ch1);
#pragma unroll
    for (int j = 0; j < 4; ++j) b[j] = *(const f16x8*)(cb + roB[j] + ch1);
    __builtin_amdgcn_s_setprio(1);
#pragma unroll
    for (int i = 0; i < 8; ++i)
#pragma unroll
      for (int j = 0; j < 4; ++j)
        acc[i][j] = __builtin_amdgcn_mfma_f32_16x16x32_f16(a[i], b[j], acc[i][j], 0, 0, 0);
    __builtin_amdgcn_s_setprio(0);
    __syncthreads();   // waits this iter's readers + drains stage tail
  }

  const int cl = lane & 15, rg = lane >> 4;
  float* po;
  if constexpr (OUT == 3) {
    po = (ks == 0) ? p0 : (ks == 1) ? p1 : (ks == 2) ? p2 : p3;
  } else {
    po = p0;
  }
#pragma unroll
  for (int i = 0; i < 8; ++i) {
#pragma unroll
    for (int r = 0; r < 4; ++r) {
      const int mloc = m0 + wm * 128 + i * 16 + rg * 4 + r;
      if (GATHER && mloc >= cnt) continue;
      const int orow = GATHER ? idx[mloc] : mloc;
#pragma unroll
      for (int j = 0; j < 4; ++j) {
        const int col = n0 + wn * 64 + j * 16 + cl;
        float v2 = acc[i][j][r];
        if (BIAS) v2 += bias[col];
        if (RELU) v2 = v2 > 0.f ? v2 : 0.f;
        if (RES) v2 += res[(size_t)orow * N + col];
        size_t oidx;
        if constexpr (QKV3) {
          if (col < 2048) {
            oidx = ((size_t)(col >> 10) * M + orow) * 1024 + (col & 1023);
          } else {
            const int c = col - 2048;  // head*64 + d
            oidx = (size_t)2 * M * 1024 +
                   (((size_t)(orow >> 10) * 16 + (c >> 6)) * 64 + (c & 63)) * 1024 +
                   (orow & 1023);
          }
        } else {
          oidx = (size_t)orow * N + col;
        }
        if constexpr (OUT == 0 || OUT == 3) {
          po[oidx] = v2;
        } else if constexpr (OUT == 1) {
          f16 hi = (f16)v2;
          outh[oidx] = hi;
          outl[oidx] = (f16)(v2 - (float)hi);
        } else {
          outh[oidx] = (f16)v2;
        }
      }
    }
  }
}

// ---------------- flash attention, causal, D=64, split-fp16 -----------------
__global__ __launch_bounds__(256, 3) void attn_k(
    const f16* __restrict__ qh, const f16* __restrict__ ql,
    const f16* __restrict__ kh, const f16* __restrict__ kl,
    const f16* __restrict__ vth, const f16* __restrict__ vtl,
    f16* __restrict__ oh, f16* __restrict__ ol) {
  const int qt = 15 - (blockIdx.x & 15), hd = (blockIdx.x >> 4) & 15, bb = blockIdx.x >> 8;
  const int tid = threadIdx.x, wave = tid >> 6, lane = tid & 63;
  __shared__ __align__(16) char QPs[16384], Ks[16384], Vs[16384];
  const int swz = (((lane & 7) ^ ((lane >> 3) & 7)) << 4);
  const size_t tok0 = (size_t)bb * 1024;
  const int hoff = hd * 64;
  const size_t vbase = ((size_t)(bb * 16 + hd) * 64) * 1024;  // v_t rows
  const float L2E = 1.44269504089f;

#pragma unroll
  for (int r = 0; r < 2; ++r) {
    const int chunk = wave * 2 + r;
    const int row = chunk * 8 + (lane >> 3);
    const size_t byte = (((tok0 + qt * 64 + row) * 1024 + hoff) << 1) + swz;
    async16(QPs + chunk * 1024, (const char*)qh + byte);
    async16(QPs + 8192 + chunk * 1024, (const char*)ql + byte);
  }
  __syncthreads();
  f16x8 qr_h[2], qr_l[2];
#pragma unroll
  for (int ks = 0; ks < 2; ++ks) {
    const int qrow = wave * 16 + (lane & 15);
    const int qoff = qrow * 128 + ((((ks << 2) + (lane >> 4)) ^ (qrow & 7)) << 4);
    qr_h[ks] = *(const f16x8*)(QPs + qoff);
    qr_l[ks] = *(const f16x8*)(QPs + 8192 + qoff);
  }

  f32x4 oacc[4] = {};
  float mrun[4] = {-1e30f, -1e30f, -1e30f, -1e30f};
  float lrun[4] = {};

  for (int kt = 0; kt <= qt; ++kt) {
    __syncthreads();
#pragma unroll
    for (int r = 0; r < 2; ++r) {
      const int chunk = wave * 2 + r;
      const int row = chunk * 8 + (lane >> 3);
      const size_t kbyte = (((tok0 + kt * 64 + row) * 1024 + hoff) << 1) + swz;
      async16(Ks + chunk * 1024, (const char*)kh + kbyte);
      async16(Ks + 8192 + chunk * 1024, (const char*)kl + kbyte);
      const size_t vbyte = (((vbase + (size_t)row * 1024) + kt * 64) << 1) + swz;
      async16(Vs + chunk * 1024, (const char*)vth + vbyte);
      async16(Vs + 8192 + chunk * 1024, (const char*)vtl + vbyte);
    }
    __syncthreads();

    f32x4 s[4] = {};
#pragma unroll
    for (int ks = 0; ks < 2; ++ks) {
#pragma unroll
      for (int j = 0; j < 4; ++j) {
        const int col = j * 16 + (lane & 15);
        const int koff = col * 128 + ((((ks << 2) + (lane >> 4)) ^ (col & 7)) << 4);
        f16x8 b_h = *(const f16x8*)(Ks + koff);
        f16x8 b_l = *(const f16x8*)(Ks + 8192 + koff);
        s[j] = __builtin_amdgcn_mfma_f32_16x16x32_f16(qr_h[ks], b_h, s[j], 0, 0, 0);
        s[j] = __builtin_amdgcn_mfma_f32_16x16x32_f16(qr_l[ks], b_h, s[j], 0, 0, 0);
        s[j] = __builtin_amdgcn_mfma_f32_16x16x32_f16(qr_h[ks], b_l, s[j], 0, 0, 0);
      }
    }

    const bool diag = (kt == qt);
    float pmax[4] = {-1e30f, -1e30f, -1e30f, -1e30f};
#pragma unroll
    for (int j = 0; j < 4; ++j)
#pragma unroll
      for (int r = 0; r < 4; ++r) {
        float sv = s[j][r] * 0.125f;
        if (diag) {
          const int qloc = wave * 16 + (lane >> 4) * 4 + r;
          const int kvl = j * 16 + (lane & 15);
          if (kvl > qloc) sv = -1e30f;
        }
        s[j][r] = sv;
        pmax[r] = fmaxf(pmax[r], sv);
      }
    char* pbh = QPs + wave * 2048;
    char* pbl = QPs + 8192 + wave * 2048;
#pragma unroll
    for (int r = 0; r < 4; ++r) {
#pragma unroll
      for (int mm = 1; mm < 16; mm <<= 1)
        pmax[r] = fmaxf(pmax[r], __shfl_xor(pmax[r], mm, 16));
      const float mnew = fmaxf(mrun[r], pmax[r]);
      const float al = exp2f((mrun[r] - mnew) * L2E);
      mrun[r] = mnew;
      lrun[r] *= al;
      oacc[0][r] *= al; oacc[1][r] *= al; oacc[2][r] *= al; oacc[3][r] *= al;
    }

    float psum[4] = {};
#pragma unroll
    for (int j = 0; j < 4; ++j)
#pragma unroll
      for (int r = 0; r < 4; ++r) {
        const float p = exp2f((s[j][r] - mrun[r]) * L2E);
        psum[r] += p;
        const int lr = (lane >> 4) * 4 + r;
        const int kvl = j * 16 + (lane & 15);
        const int poff = lr * 128 + ((kvl * 2) ^ ((lr & 7) << 4));
        f16 ph = (f16)p;
        *(f16*)(pbh + poff) = ph;
        *(f16*)(pbl + poff) = (f16)(p - (float)ph);
      }
#pragma unroll
    for (int r = 0; r < 4; ++r) {
#pragma unroll
      for (int mm = 1; mm < 16; mm <<= 1)
        psum[r] += __shfl_xor(psum[r], mm, 16);
      lrun[r] += psum[r];
    }

#pragma unroll
    for (int ks = 0; ks < 2; ++ks) {
      const int prow = lane & 15;
      const int poff = prow * 128 + ((((ks << 2) + (lane >> 4)) ^ (prow & 7)) << 4);
      f16x8 a_h = *(const f16x8*)(pbh + poff);
      f16x8 a_l = *(const f16x8*)(pbl + poff);
#pragma unroll
      for (int jd = 0; jd < 4; ++jd) {
        const int col = jd * 16 + (lane & 15);
        const int voff = col * 128 + ((((ks << 2) + (lane >> 4)) ^ (col & 7)) << 4);
        f16x8 b_h = *(const f16x8*)(Vs + voff);
        f16x8 b_l = *(const f16x8*)(Vs + 8192 + voff);
        oacc[jd] = __builtin_amdgcn_mfma_f32_16x16x32_f16(a_h, b_h, oacc[jd], 0, 0, 0);
        oacc[jd] = __builtin_amdgcn_mfma_f32_16x16x32_f16(a_l, b_h, oacc[jd], 0, 0, 0);
        oacc[jd] = __builtin_amdgcn_mfma_f32_16x16x32_f16(a_h, b_l, oacc[jd], 0, 0, 0);
      }
    }
  }

#pragma unroll
  for (int r = 0; r < 4; ++r) {
    const float inv = 1.0f / lrun[r];
    const size_t trow = tok0 + qt * 64 + wave * 16 + (lane >> 4) * 4 + r;
#pragma unroll
    for (int jd = 0; jd < 4; ++jd) {
      const int col = hoff + jd * 16 + (lane & 15);
      const float val = oacc[jd][r] * inv;
      const f16 hi = (f16)val;
      oh[trow * 1024 + col] = hi;
      ol[trow * 1024 + col] = (f16)(val - (float)hi);
    }
  }
}

// ---------------------------------------------------------------------------
extern "C" void kernel_launch(void* const* d_in, const int* in_sizes, int n_in,
                              void* d_out, int out_size, void* d_ws, size_t ws_size,
                              hipStream_t stream) {
  const float* x0   = (const float*)d_in[0];
  const float* wq   = (const float*)d_in[1];
  const float* wk   = (const float*)d_in[2];
  const float* wv   = (const float*)d_in[3];
  const float* wo   = (const float*)d_in[4];
  const float* bo   = (const float*)d_in[5];
  const float* ffw1 = (const float*)d_in[6];
  const float* ffb1 = (const float*)d_in[7];
  const float* ffw2 = (const float*)d_in[8];
  const float* ffb2 = (const float*)d_in[9];
  const float* ew1  = (const float*)d_in[10];
  const float* eb1  = (const float*)d_in[11];
  const float* ew2  = (const float*)d_in[12];
  const float* eb2  = (const float*)d_in[13];
  const float* gw   = (const float*)d_in[14];
  const float* gb   = (const float*)d_in[15];
  const float* l1g  = (const float*)d_in[16];
  const float* l1b  = (const float*)d_in[17];
  const float* l2g  = (const float*)d_in[18];
  const float* l2b  = (const float*)d_in[19];
  const float* l3g  = (const float*)d_in[20];
  const float* l3b  = (const float*)d_in[21];
  float* out = (float*)d_out;

  char* w = (char*)d_ws;
  const size_t M1 = (size_t)1024 * 1024;       // elems of a 1024x1024 f16
  const size_t A1 = (size_t)4096 * 1024 * 2;   // 8MB  (f16 4096x1024)
  const size_t W4 = (size_t)1024 * 4096 * 2;   // 8MB  (f16 1024x4096)
  f16* wqkvh = (f16*)w; w += 3 * M1 * 2;       // 6MB
  f16* wqkvl = (f16*)w; w += 3 * M1 * 2;       // 6MB
  f16* woh = (f16*)w; w += M1 * 2;             // 2MB
  f16* wol = (f16*)w; w += M1 * 2;             // 2MB   (wqkvh..wol = 16MB)
  f16* f1h = (f16*)w; w += W4;  f16* f1l = (f16*)w; w += W4;   // 16MB
  f16* f2h = (f16*)w; w += W4;  f16* f2l = (f16*)w; w += W4;
  f16* e1t = (f16*)w; w += 4 * W4;
  f16* e2t = (f16*)w; w += 4 * W4;
  f16* hh  = (f16*)w; w += A1;  f16* hl  = (f16*)w; w += A1;   // 16MB
  f16* qkv_h = (f16*)w; w += 3 * A1;           // 24MB (q,k row-major; v_t)
  f16* qkv_l = (f16*)w; w += 3 * A1;           // 24MB
  f16* o_h = (f16*)w; w += A1;  f16* o_l = (f16*)w; w += A1;   // 16MB
  float* x1 = (float*)w; w += (size_t)4096 * 1024 * 4;         // 16MB
  float* extraP = (float*)w; w += (size_t)4096 * 1024 * 4;     // 16MB
  int* cnt = (int*)w; w += 256;
  int* idx = (int*)w; w += (size_t)4 * 4096 * 4;
  int* eid = (int*)w; w += (size_t)4096 * 4;
  int* desc = (int*)w; w += 256;
  // aliases over sequentially-dead regions:
  f16* hid_h = qkv_h;                                       // FF hidden hi 32MB
  f16* hid_l = (f16*)((char*)qkv_h + (((size_t)32) << 20)); // FF hidden lo 32MB
  f16* ffh   = qkv_h;                                       // MoE hidden 32MB
  const size_t MB16 = ((size_t)16) << 20;
  // wo partials: qkv region (48MB) + hh/hl (16MB), all dead post-attn
  float* wP0 = (float*)qkv_h;
  float* wP1 = (float*)((char*)qkv_h + MB16);
  float* wP2 = (float*)((char*)qkv_h + 2 * MB16);
  float* wP3 = (float*)hh;
  // ff2 partials: wqkv+wo (16MB), f1 (16MB), hh/hl (16MB), extra
  float* fP0 = (float*)wqkvh;
  float* fP1 = (float*)f1h;
  float* fP2 = (float*)hh;
  float* fP3 = extraP;
  // moe-down partials: hh/hl, o, x1 (dead post-ff2-reduce), extra
  float* mP0 = (float*)hh;
  float* mP1 = (float*)o_h;
  float* mP2 = x1;
  float* mP3 = extraP;

  // ---- weights -> f16 (split for pre-gate, single for experts) ----
  transpose_k<true><<<1024, 256, 0, stream>>>(wq, wqkvh, wqkvl, 1024, 1024);
  transpose_k<true><<<1024, 256, 0, stream>>>(wk, wqkvh + M1, wqkvl + M1, 1024, 1024);
  transpose_k<true><<<1024, 256, 0, stream>>>(wv, wqkvh + 2 * M1, wqkvl + 2 * M1, 1024, 1024);
  transpose_k<true><<<1024, 256, 0, stream>>>(wo, woh, wol, 1024, 1024);
  transpose_k<true><<<4096, 256, 0, stream>>>(ffw1, f1h, f1l, 1024, 4096);
  transpose_k<true><<<4096, 256, 0, stream>>>(ffw2, f2h, f2l, 4096, 1024);
  transpose_k<false><<<dim3(4096, 4), 256, 0, stream>>>(ew1, e1t, nullptr, 1024, 4096);
  transpose_k<false><<<dim3(4096, 4), 256, 0, stream>>>(ew2, e2t, nullptr, 4096, 1024);

  const size_t TOK = (size_t)4096 * 1024;
  // ---- attention ----
  ln_k<<<4096, 256, 0, stream>>>(x0, l1g, l1b, hh, hl);
  gemm_k<true, false, false, false, false, 1, true, 1><<<192, 512, 0, stream>>>(
      hh, hl, wqkvh, wqkvl, nullptr, nullptr, nullptr, nullptr, qkv_h, qkv_l,
      nullptr, nullptr, nullptr, nullptr, nullptr, 4096, 3072, 1024);
  attn_k<<<1024, 256, 0, stream>>>(qkv_h, qkv_l, qkv_h + TOK, qkv_l + TOK,
                                   qkv_h + 2 * TOK, qkv_l + 2 * TOK, o_h, o_l);
  gemm_k<true, false, false, false, false, 3, false, 4><<<256, 512, 0, stream>>>(
      o_h, o_l, woh, wol, wP0, wP1, wP2, wP3, nullptr, nullptr,
      nullptr, nullptr, nullptr, nullptr, nullptr, 4096, 1024, 1024);
  reduce_k<false><<<4096, 256, 0, stream>>>(wP0, wP1, wP2, wP3, x0, bo, nullptr, x1);

  // ---- dense FFN ----
  ln_k<<<4096, 256, 0, stream>>>(x1, l2g, l2b, hh, hl);
  gemm_k<true, true, true, false, false, 1, false, 1><<<256, 512, 0, stream>>>(
      hh, hl, f1h, f1l, nullptr, nullptr, nullptr, nullptr, hid_h, hid_l,
      ffb1, nullptr, nullptr, nullptr, nullptr, 4096, 4096, 1024);
  gemm_k<true, false, false, false, false, 3, false, 4><<<256, 512, 0, stream>>>(
      hid_h, hid_l, f2h, f2l, fP0, fP1, fP2, fP3, nullptr, nullptr,
      nullptr, nullptr, nullptr, nullptr, nullptr, 4096, 1024, 4096);
  reduce_k<false><<<4096, 256, 0, stream>>>(fP0, fP1, fP2, fP3, x1, ffb2, nullptr, out);

  // ---- MoE (top-1 routed; gate in pure f32; dense 256-row tile plan) ----
  ln_k<<<4096, 256, 0, stream>>>(out, l3g, l3b, hh, hl);
  init_moe<<<1, 64, 0, stream>>>(cnt);
  gate_k<<<4096, 256, 0, stream>>>(out, l3g, l3b, gw, gb, cnt, idx, eid);
  plan_k<<<1, 64, 0, stream>>>(cnt, desc);
  gemm_k<false, true, true, false, true, 2, false, 1><<<MAXMT * 16, 512, 0, stream>>>(
      hh, nullptr, e1t, nullptr, nullptr, nullptr, nullptr, nullptr, ffh, nullptr,
      eb1, nullptr, idx, cnt, desc, 4096, 4096, 1024);
  gemm_k<false, false, false, false, true, 3, false, 4><<<4 * MAXMT * 4, 512, 0, stream>>>(
      ffh, nullptr, e2t, nullptr, mP0, mP1, mP2, mP3, nullptr, nullptr,
      nullptr, nullptr, idx, cnt, desc, 4096, 1024, 4096);
  reduce_k<true><<<4096, 256, 0, stream>>>(mP0, mP1, mP2, mP3, out, eb2, eid, out);
}